// Round 17
// baseline (296.402 us; speedup 1.0000x reference)
//
#include <hip/hip_runtime.h>

// Problem constants (fixed by setup_inputs)
#define N_NODES 8192
#define N_EDGES 65536
#define NS 64    // node state: 2 halves of 32 floats (27 used + pad); ch c class g at (c/9)*32+(c%9)*3+g
// flux16: CSR-slot layout [2E slots][64 halves] — one 128B cache line per endpoint contribution.

// Workspace layout (word offsets into d_ws)
#define XN3_OFF   0                                   // [8192][64] floats
#define MIT_OFF   (N_NODES*NS)                        // [5][2 stages][36 c][4 q][20] floats
#define K2N_OFF   (MIT_OFF + 5*5760)                  // [2][16][16]
#define KNC_OFF   (K2N_OFF + 2*16*16)                 // [2][3][18]
#define K2E_OFF   (KNC_OFF + 2*3*18)                  // [2]
#define FLUX_OFF  553728                              // 16B-aligned; [2E][32] u32 (fp16 pairs)
#define FLUX_END  (FLUX_OFF + 2*N_EDGES*32)
#define DEG_OFF   FLUX_END
#define RP_OFF    (DEG_OFF + N_NODES)
#define FP_OFF    (RP_OFF + N_NODES + 1)
#define POSI_OFF  (FP_OFF + N_NODES)
#define POSJ_OFF  (POSI_OFF + N_EDGES)

typedef float f32x2 __attribute__((ext_vector_type(2)));
typedef __fp16 fp16x2 __attribute__((ext_vector_type(2)));

__device__ __forceinline__ unsigned pkrtz(float a, float b) {
    fp16x2 h = __builtin_amdgcn_cvt_pkrtz(a, b);
    return *(unsigned*)&h;
}

template<int SLOT>
__device__ __forceinline__ float qb(float x) {
    int r = __builtin_amdgcn_update_dpp(0, __float_as_int(x), SLOT * 0x55, 0xf, 0xf, true);
    return __int_as_float(r);
}
__device__ __forceinline__ float qswap2(float x) {
    int r = __builtin_amdgcn_update_dpp(0, __float_as_int(x), 0x4E, 0xf, 0xf, true);
    return __int_as_float(r);
}

__device__ __forceinline__ void vrelu_p(float& a0, f32x2& a12,
                                        float q0, f32x2 q12, float iq2) {
    float t = fmaf(a0, q0, fmaf(a12.x, q12.x, a12.y * q12.y));
    float r = t > 0.f ? t * iq2 : 0.f;
    a0 = fmaf(-r, q0, a0);
    f32x2 nr = {-r, -r};
    a12 = nr * q12 + a12;
}

__device__ __forceinline__ void vrelu3(float& x0, float& x1, float& x2,
                                       float q0, float q1, float q2, float iq2) {
    float t = x0*q0 + x1*q1 + x2*q2;
    float r = t > 0.f ? t*iq2 : 0.f;
    x0 = fmaf(-r, q0, x0);
    x1 = fmaf(-r, q1, x1);
    x2 = fmaf(-r, q2, x2);
}

// one quarter of the 36-channel matvec for TWO edges sharing each LDS matrix row read.
template<int QS>
__device__ __forceinline__ void matvec2(const float* __restrict__ mbase, int q,
        const float (&v0a)[9], const f32x2 (&v12a)[9],
        const float (&v0b)[9], const f32x2 (&v12b)[9],
        f32x2 (&a0pa)[4], float& a0sa, f32x2 (&a12a)[9],
        f32x2 (&a0pb)[4], float& a0sb, f32x2 (&a12b)[9]) {
    const float* rb = mbase + QS*720 + q*20;
#pragma unroll
    for (int kc = 0; kc < 9; ++kc) {
        float b0a = qb<QS>(v0a[kc]);
        f32x2 b12a; b12a.x = qb<QS>(v12a[kc].x); b12a.y = qb<QS>(v12a[kc].y);
        float b0b = qb<QS>(v0b[kc]);
        f32x2 b12b; b12b.x = qb<QS>(v12b[kc].x); b12b.y = qb<QS>(v12b[kc].y);
        f32x2 bb0a = {b0a, b0a};
        f32x2 bb0b = {b0b, b0b};
        const float4* rp = (const float4*)(rb + kc*80);
        float4 R0 = rp[0], R1 = rp[1], R2 = rp[2], R3 = rp[3], R4 = rp[4];
        f32x2 m0p[4] = {{R0.x,R0.y},{R0.z,R0.w},{R1.x,R1.y},{R1.z,R1.w}};
        float mA[9] = {R2.z,R2.w,R3.x,R3.y,R3.z,R3.w,R4.x,R4.y,R4.z};
#pragma unroll
        for (int k = 0; k < 4; ++k) {
            a0pa[k] = m0p[k] * bb0a + a0pa[k];
            a0pb[k] = m0p[k] * bb0b + a0pb[k];
        }
        a0sa = fmaf(R2.x, b0a, a0sa);
        a0sb = fmaf(R2.x, b0b, a0sb);
#pragma unroll
        for (int k = 0; k < 9; ++k) {
            f32x2 mm = {mA[k], mA[k]};
            a12a[k] = mm * b12a + a12a[k];
            a12b[k] = mm * b12b + a12b[k];
        }
    }
}

// ---------------- precompute reduced matrices (+ zero deg) ----------------
__global__ void precompute_kernel(const float* __restrict__ K2N,
                                  const float* __restrict__ K2E,
                                  const float* __restrict__ KE1,
                                  const float* __restrict__ KE2,
                                  const float* __restrict__ KNc,
                                  float* __restrict__ ws,
                                  int* __restrict__ deg) {
    int tid = blockIdx.x * blockDim.x + threadIdx.x;
    int nthr = gridDim.x * blockDim.x;
    if (tid < N_NODES) deg[tid] = 0;
    for (int m = tid; m < 1440; m += nthr) {
        ws[MIT_OFF + m*20 + 9]  = 0.f;
        ws[MIT_OFF + m*20 + 19] = 0.f;
    }
    for (int m = tid; m < 5*1296; m += nthr) {
        int l = m / 1296, oc = m % 1296;
        int o = oc / 36, c = oc % 36;
        int qq = o / 9, k = o % 9;
        const float* p1 = KE1 + (size_t)(l*1296 + oc)*6;
        const float* p2 = KE2 + (size_t)(l*1296 + oc)*6;
        int base = MIT_OFF + l*5760 + (c*4 + qq)*20;
        ws[base + k]             = p1[0] + p1[1] + p1[2];
        ws[base + 10 + k]        = p1[3] + p1[4] + p1[5];
        ws[base + 2880 + k]      = p2[0] + p2[1] + p2[2];
        ws[base + 2880 + 10 + k] = p2[3] + p2[4] + p2[5];
    }
    for (int m = tid; m < 2*256; m += nthr) {
        int s = m / 256, oc = m % 256;
        const float* p = K2N + oc*6 + 3*s;
        ws[K2N_OFF + m] = p[0] + p[1] + p[2];
    }
    for (int m = tid; m < 2*54; m += nthr) {
        int s = m / 54, oc = m % 54;
        const float* p = KNc + oc*6 + 3*s;
        ws[KNC_OFF + m] = p[0] + p[1] + p[2];
    }
    if (tid < 2) {
        const float* p = K2E + 3*tid;
        ws[K2E_OFF + tid] = p[0] + p[1] + p[2];
    }
}

// ---------------- CSR build ----------------
__global__ void count_kernel(const int* __restrict__ iInd, const int* __restrict__ jInd,
                             int* __restrict__ deg) {
    int e = blockIdx.x * blockDim.x + threadIdx.x;
    if (e >= N_EDGES) return;
    atomicAdd(&deg[iInd[e]], 1);
    atomicAdd(&deg[jInd[e]], 1);
}

__global__ void scan_kernel(const int* __restrict__ deg, int* __restrict__ rowptr,
                            int* __restrict__ fpos) {
    __shared__ int lds[256];
    int t = threadIdx.x;
    int base = t * 32;
    int s = 0;
#pragma unroll
    for (int k = 0; k < 32; ++k) s += deg[base + k];
    lds[t] = s;
    __syncthreads();
    if (t == 0) {
        int run = 0;
        for (int k = 0; k < 256; ++k) { int v = lds[k]; lds[k] = run; run += v; }
        rowptr[N_NODES] = run;
    }
    __syncthreads();
    int off = lds[t];
#pragma unroll
    for (int k = 0; k < 32; ++k) {
        rowptr[base + k] = off;
        fpos[base + k] = off;
        off += deg[base + k];
    }
}

__global__ void fill_kernel(const int* __restrict__ iInd, const int* __restrict__ jInd,
                            int* __restrict__ fpos,
                            int* __restrict__ posI, int* __restrict__ posJ) {
    int e = blockIdx.x * blockDim.x + threadIdx.x;
    if (e >= N_EDGES) return;
    posI[e] = atomicAdd(&fpos[iInd[e]], 1);
    posJ[e] = atomicAdd(&fpos[jInd[e]], 1);
}

// ---------------- opening: node (blocks 0..31) + edge (blocks 32..287) ----------------
__global__ void open_kernel(const float* __restrict__ xnV,
                            const float* __restrict__ xeV,
                            const float* __restrict__ Q,
                            const float* __restrict__ K1N,
                            const float* __restrict__ K1E,
                            const float* __restrict__ ws,
                            const int* __restrict__ posI, const int* __restrict__ posJ,
                            float* __restrict__ xn3,
                            float4* __restrict__ seslot) {
    float q0 = Q[0], q1 = Q[1], q2 = Q[2];
    float iq2 = 1.f / (q0*q0 + q1*q1 + q2*q2);

    if (blockIdx.x < 32) {
        int n = blockIdx.x * 256 + threadIdx.x;
        float R[3][9];
#pragma unroll
        for (int c = 0; c < 3; ++c)
#pragma unroll
            for (int p = 0; p < 9; ++p)
                R[c][p] = xnV[(c*9 + p)*N_NODES + n];
#pragma unroll
        for (int c = 0; c < 3; ++c)
#pragma unroll
            for (int v = 0; v < 3; ++v)
                vrelu3(R[c][3*v], R[c][3*v+1], R[c][3*v+2], q0, q1, q2, iq2);

        float s[16][3];
#pragma unroll
        for (int o = 0; o < 16; ++o) {
            float a0 = 0.f, a1 = 0.f, a2 = 0.f;
#pragma unroll
            for (int c = 0; c < 3; ++c)
#pragma unroll
                for (int g = 0; g < 3; ++g) {
                    a0 = fmaf(R[c][3*g + 0], K1N[(o*3 + c)*6 + g],     a0);
                    a1 = fmaf(R[c][3*g + 1], K1N[(o*3 + c)*6 + 3 + g], a1);
                    a2 = fmaf(R[c][3*g + 2], K1N[(o*3 + c)*6 + 3 + g], a2);
                }
            s[o][0] = a0; s[o][1] = a1; s[o][2] = a2;
        }
#pragma unroll
        for (int o = 0; o < 16; ++o)
            vrelu3(s[o][0], s[o][1], s[o][2], q0, q1, q2, iq2);

        float u[16][3];
#pragma unroll
        for (int o = 0; o < 16; ++o) {
            float a0 = 0.f, a1 = 0.f, a2 = 0.f;
#pragma unroll
            for (int c = 0; c < 16; ++c) {
                float m0 = ws[K2N_OFF + o*16 + c];
                float mA = ws[K2N_OFF + 256 + o*16 + c];
                a0 = fmaf(m0, s[c][0], a0);
                a1 = fmaf(mA, s[c][1], a1);
                a2 = fmaf(mA, s[c][2], a2);
            }
            u[o][0] = a0; u[o][1] = a1; u[o][2] = a2;
            vrelu3(u[o][0], u[o][1], u[o][2], q0, q1, q2, iq2);
        }

        float* dst = xn3 + n*NS;
#pragma unroll
        for (int o = 0; o < 16; ++o) {
            int base = (o/9)*32 + (o%9)*3;
#pragma unroll
            for (int g = 0; g < 3; ++g)
                dst[base + g] = u[o][g];
        }
#pragma unroll
        for (int k = 27; k < 32; ++k) dst[k] = 0.f;
    } else {
        int e = (blockIdx.x - 32) * 256 + threadIdx.x;
        float R[9];
#pragma unroll
        for (int p = 0; p < 9; ++p) R[p] = xeV[p*N_EDGES + e];
#pragma unroll
        for (int v = 0; v < 3; ++v)
            vrelu3(R[3*v], R[3*v+1], R[3*v+2], q0, q1, q2, iq2);

        float s0 = 0.f, s1 = 0.f, s2 = 0.f;
#pragma unroll
        for (int g = 0; g < 3; ++g) {
            s0 = fmaf(R[3*g + 0], K1E[g],     s0);
            s1 = fmaf(R[3*g + 1], K1E[3 + g], s1);
            s2 = fmaf(R[3*g + 2], K1E[3 + g], s2);
        }
        vrelu3(s0, s1, s2, q0, q1, q2, iq2);
        s0 *= ws[K2E_OFF + 0];
        s1 *= ws[K2E_OFF + 1];
        s2 *= ws[K2E_OFF + 1];
        vrelu3(s0, s1, s2, q0, q1, q2, iq2);

        seslot[posI[e]] = make_float4( s0,  s1,  s2,  1.f);
        seslot[posJ[e]] = make_float4(-s0, -s1, -s2, -1.f);
    }
}

// gather edge-open contributions into xn3 channels 16,17 — streaming CSR reads
__global__ void open_gather_kernel(const float4* __restrict__ seslot,
                                   const int* __restrict__ rowptr,
                                   float* __restrict__ xn3) {
    int n = blockIdx.x * blockDim.x + threadIdx.x;
    if (n >= N_NODES) return;
    int beg = rowptr[n], end = rowptr[n + 1];
    float d0 = 0.f, d1 = 0.f, d2 = 0.f, a0 = 0.f, a1 = 0.f, a2 = 0.f;
    for (int d = beg; d < end; ++d) {
        float4 v = seslot[d];
        d0 += v.x; d1 += v.y; d2 += v.z;
        float hs = 0.5f * v.w;
        a0 = fmaf(hs, v.x, a0); a1 = fmaf(hs, v.y, a1); a2 = fmaf(hs, v.z, a2);
    }
    float* dst = xn3 + n*NS;
    dst[53] = d0; dst[54] = d1; dst[55] = d2;
    dst[56] = a0; dst[57] = a1; dst[58] = a2;
#pragma unroll
    for (int k = 59; k < 64; ++k) dst[k] = 0.f;
}

// ---------------- per-layer phase A: 2 edges per thread-quad member ----------------
// MW template: within-run A/B of min-waves/EU (2 = round-9 proven; 3 = +50% latency hiding IF
// the allocator keeps ~168 VGPRs without dropping to the 128-spill bucket).
template<bool WRITE_FLUX, int MW>
__global__ __launch_bounds__(256, MW) void edge_compute_kernel(
        const float* __restrict__ xn3,
        const int* __restrict__ iInd, const int* __restrict__ jInd,
        const int* __restrict__ posI, const int* __restrict__ posJ,
        const float* __restrict__ Q,
        const float* __restrict__ mitg,   // [2][36][4][20]
        unsigned* __restrict__ flux16, float* __restrict__ fluxOut) {
    __shared__ float mit[5760];
    {
        const float4* s4 = (const float4*)mitg;
        float4* d4 = (float4*)mit;
        for (int t = threadIdx.x; t < 1440; t += 256) d4[t] = s4[t];
    }
    __syncthreads();

    int tid = blockIdx.x * 256 + threadIdx.x;
    int qd = tid >> 2, q = tid & 3;
    int e0 = qd << 1, e1 = e0 | 1;
    float q0 = Q[0];
    f32x2 q12 = {Q[1], Q[2]};
    float iq2 = 1.f / (q0*q0 + q12.x*q12.x + q12.y*q12.y);
    int hofs = 32*(q & 1);
    const float4* xi0 = (const float4*)(xn3 + iInd[e0]*NS + hofs);
    const float4* xj0 = (const float4*)(xn3 + jInd[e0]*NS + hofs);
    const float4* xi1 = (const float4*)(xn3 + iInd[e1]*NS + hofs);
    const float4* xj1 = (const float4*)(xn3 + jInd[e1]*NS + hofs);

    bool isAve = q >= 2;
    float sA = isAve ? 0.5f :  1.f;
    float sB = isAve ? 0.5f : -1.f;

    float vvA[28], vvB[28];
#pragma unroll
    for (int t = 0; t < 7; ++t) {
        float4 a = xi0[t], b = xj0[t];
        vvA[4*t+0] = fmaf(sA, a.x, sB * b.x);
        vvA[4*t+1] = fmaf(sA, a.y, sB * b.y);
        vvA[4*t+2] = fmaf(sA, a.z, sB * b.z);
        vvA[4*t+3] = fmaf(sA, a.w, sB * b.w);
        float4 c = xi1[t], d = xj1[t];
        vvB[4*t+0] = fmaf(sA, c.x, sB * d.x);
        vvB[4*t+1] = fmaf(sA, c.y, sB * d.y);
        vvB[4*t+2] = fmaf(sA, c.z, sB * d.z);
        vvB[4*t+3] = fmaf(sA, c.w, sB * d.w);
    }

    float v0a[9], v0b[9]; f32x2 v12a[9], v12b[9];
#pragma unroll
    for (int k = 0; k < 9; ++k) {
        v0a[k]    = vvA[3*k];
        v12a[k].x = vvA[3*k+1];
        v12a[k].y = vvA[3*k+2];
        vrelu_p(v0a[k], v12a[k], q0, q12, iq2);
        v0b[k]    = vvB[3*k];
        v12b[k].x = vvB[3*k+1];
        v12b[k].y = vvB[3*k+2];
        vrelu_p(v0b[k], v12b[k], q0, q12, iq2);
    }

    f32x2 a0pa[4], a0pb[4]; float a0sa, a0sb; f32x2 a12a[9], a12b[9];
#pragma unroll
    for (int k = 0; k < 4; ++k) { a0pa[k] = (f32x2){0.f,0.f}; a0pb[k] = (f32x2){0.f,0.f}; }
    a0sa = 0.f; a0sb = 0.f;
#pragma unroll
    for (int k = 0; k < 9; ++k) { a12a[k] = (f32x2){0.f,0.f}; a12b[k] = (f32x2){0.f,0.f}; }
    matvec2<0>(mit, q, v0a, v12a, v0b, v12b, a0pa, a0sa, a12a, a0pb, a0sb, a12b);
    matvec2<1>(mit, q, v0a, v12a, v0b, v12b, a0pa, a0sa, a12a, a0pb, a0sb, a12b);
    matvec2<2>(mit, q, v0a, v12a, v0b, v12b, a0pa, a0sa, a12a, a0pb, a0sb, a12b);
    matvec2<3>(mit, q, v0a, v12a, v0b, v12b, a0pa, a0sa, a12a, a0pb, a0sb, a12b);
#pragma unroll
    for (int k = 0; k < 9; ++k) {
        float w0 = (k < 8) ? ((k & 1) ? a0pa[k>>1].y : a0pa[k>>1].x) : a0sa;
        f32x2 w12 = a12a[k];
        vrelu_p(w0, w12, q0, q12, iq2);
        v0a[k] = w0; v12a[k] = w12;
        float u0 = (k < 8) ? ((k & 1) ? a0pb[k>>1].y : a0pb[k>>1].x) : a0sb;
        f32x2 u12 = a12b[k];
        vrelu_p(u0, u12, q0, q12, iq2);
        v0b[k] = u0; v12b[k] = u12;
    }
#pragma unroll
    for (int k = 0; k < 4; ++k) { a0pa[k] = (f32x2){0.f,0.f}; a0pb[k] = (f32x2){0.f,0.f}; }
    a0sa = 0.f; a0sb = 0.f;
#pragma unroll
    for (int k = 0; k < 9; ++k) { a12a[k] = (f32x2){0.f,0.f}; a12b[k] = (f32x2){0.f,0.f}; }
    matvec2<0>(mit + 2880, q, v0a, v12a, v0b, v12b, a0pa, a0sa, a12a, a0pb, a0sb, a12b);
    matvec2<1>(mit + 2880, q, v0a, v12a, v0b, v12b, a0pa, a0sa, a12a, a0pb, a0sb, a12b);
    matvec2<2>(mit + 2880, q, v0a, v12a, v0b, v12b, a0pa, a0sa, a12a, a0pb, a0sb, a12b);
    matvec2<3>(mit + 2880, q, v0a, v12a, v0b, v12b, a0pa, a0sa, a12a, a0pb, a0sb, a12b);

#pragma unroll
    for (int k = 0; k < 9; ++k) {
        float w0 = (k < 8) ? ((k & 1) ? a0pa[k>>1].y : a0pa[k>>1].x) : a0sa;
        f32x2 w12 = a12a[k];
        vrelu_p(w0, w12, q0, q12, iq2);
        v0a[k] = w0; v12a[k] = w12;
        float u0 = (k < 8) ? ((k & 1) ? a0pb[k>>1].y : a0pb[k>>1].x) : a0sb;
        f32x2 u12 = a12b[k];
        vrelu_p(u0, u12, q0, q12, iq2);
        v0b[k] = u0; v12b[k] = u12;
    }

    float selO = (q < 2) ? 1.f  : 0.5f;
    float selP = (q < 2) ? 0.5f : -1.f;
    {
        float o27[27];
        unsigned pk[16];
#pragma unroll
        for (int k = 0; k < 9; ++k) {
            float o0 = qswap2(v0a[k]);
            float o1 = qswap2(v12a[k].x);
            float o2 = qswap2(v12a[k].y);
            o27[3*k]   = fmaf(selO, v0a[k],    selP * o0);
            o27[3*k+1] = fmaf(selO, v12a[k].x, selP * o1);
            o27[3*k+2] = fmaf(selO, v12a[k].y, selP * o2);
        }
#pragma unroll
        for (int t = 0; t < 13; ++t) pk[t] = pkrtz(o27[2*t], o27[2*t+1]);
        pk[13] = pkrtz(o27[26], 0.f);
        pk[14] = 0u; pk[15] = 0u;
        int slot = (q < 2) ? posI[e0] : posJ[e0];
        uint4* dst = (uint4*)(flux16 + (size_t)slot*32 + (q & 1)*16);
        dst[0] = make_uint4(pk[0],  pk[1],  pk[2],  pk[3]);
        dst[1] = make_uint4(pk[4],  pk[5],  pk[6],  pk[7]);
        dst[2] = make_uint4(pk[8],  pk[9],  pk[10], pk[11]);
        dst[3] = make_uint4(pk[12], pk[13], pk[14], pk[15]);
    }
    {
        float o27[27];
        unsigned pk[16];
#pragma unroll
        for (int k = 0; k < 9; ++k) {
            float o0 = qswap2(v0b[k]);
            float o1 = qswap2(v12b[k].x);
            float o2 = qswap2(v12b[k].y);
            o27[3*k]   = fmaf(selO, v0b[k],    selP * o0);
            o27[3*k+1] = fmaf(selO, v12b[k].x, selP * o1);
            o27[3*k+2] = fmaf(selO, v12b[k].y, selP * o2);
        }
#pragma unroll
        for (int t = 0; t < 13; ++t) pk[t] = pkrtz(o27[2*t], o27[2*t+1]);
        pk[13] = pkrtz(o27[26], 0.f);
        pk[14] = 0u; pk[15] = 0u;
        int slot = (q < 2) ? posI[e1] : posJ[e1];
        uint4* dst = (uint4*)(flux16 + (size_t)slot*32 + (q & 1)*16);
        dst[0] = make_uint4(pk[0],  pk[1],  pk[2],  pk[3]);
        dst[1] = make_uint4(pk[4],  pk[5],  pk[6],  pk[7]);
        dst[2] = make_uint4(pk[8],  pk[9],  pk[10], pk[11]);
        dst[3] = make_uint4(pk[12], pk[13], pk[14], pk[15]);
    }

    if (WRITE_FLUX) {
#pragma unroll
        for (int k = 0; k < 9; ++k) {
#pragma unroll
            for (int p = 0; p < 9; ++p) {
                float wa = (p % 3 == 0) ? v0a[k] : (p % 3 == 1) ? v12a[k].x : v12a[k].y;
                fluxOut[((size_t)((9*q + k)*9 + p))*N_EDGES + e0] = wa;
                float wb = (p % 3 == 0) ? v0b[k] : (p % 3 == 1) ? v12b[k].x : v12b[k].y;
                fluxOut[((size_t)((9*q + k)*9 + p))*N_EDGES + e1] = wb;
            }
        }
    }
}

// ---------------- per-layer phase B: wave-per-node streaming fp16 gather + xn update ----------------
__global__ __launch_bounds__(64) void node_gather_kernel(
        const __fp16* __restrict__ flux16,
        const int* __restrict__ rowptr,
        float* __restrict__ xn3) {
    int n = blockIdx.x;
    int l = threadIdx.x;
    int beg = rowptr[n], end = rowptr[n + 1];
    const __fp16* p = flux16 + (size_t)beg * 64 + l;
    float acc = 0.f, acc2 = 0.f;
    int d = beg;
    for (; d + 2 <= end; d += 2) {
        acc  += (float)p[0];
        acc2 += (float)p[64];
        p += 128;
    }
    if (d < end) acc += (float)p[0];
    acc += acc2;
    if ((l & 31) < 27) {
        float* x = xn3 + n*NS + l;
        *x = fmaf(-0.1f, acc, *x);
    }
}

// ---------------- layer-4 phase B fused with close ----------------
__global__ __launch_bounds__(64) void node_gather_close_kernel(
        const __fp16* __restrict__ flux16,
        const int* __restrict__ rowptr,
        const float* __restrict__ xn3,
        const float* __restrict__ ws,     // KNC at KNC_OFF
        float* __restrict__ out) {
    __shared__ float xl[64];
    int n = blockIdx.x;
    int l = threadIdx.x;
    int beg = rowptr[n], end = rowptr[n + 1];
    const __fp16* p = flux16 + (size_t)beg * 64 + l;
    float acc = 0.f, acc2 = 0.f;
    int d = beg;
    for (; d + 2 <= end; d += 2) {
        acc  += (float)p[0];
        acc2 += (float)p[64];
        p += 128;
    }
    if (d < end) acc += (float)p[0];
    acc += acc2;
    float xv = 0.f;
    if ((l & 31) < 27)
        xv = fmaf(-0.1f, acc, xn3[n*NS + l]);
    xl[l] = xv;
    __syncthreads();

    if (l < 27) {
        int oo = l / 9, pp = l % 9, g = pp % 3;
        int mbase = KNC_OFF + (g == 0 ? 0 : 54) + oo*18;
        float a = 0.f;
#pragma unroll
        for (int c = 0; c < 18; ++c)
            a = fmaf(ws[mbase + c], xl[(c/9)*32 + (c%9)*3 + g], a);
        out[(oo*9 + pp)*N_NODES + n] = a;
    }
}

extern "C" void kernel_launch(void* const* d_in, const int* in_sizes, int n_in,
                              void* d_out, int out_size, void* d_ws, size_t ws_size,
                              hipStream_t stream) {
    const float* xnV = (const float*)d_in[0];
    const float* xeV = (const float*)d_in[1];
    const int*   iInd = (const int*)d_in[2];
    const int*   jInd = (const int*)d_in[3];
    const float* K1N = (const float*)d_in[4];
    const float* K2N = (const float*)d_in[5];
    const float* K1E = (const float*)d_in[6];
    const float* K2E = (const float*)d_in[7];
    const float* KE1 = (const float*)d_in[8];
    const float* KE2 = (const float*)d_in[9];
    const float* KNc = (const float*)d_in[10];
    const float* Q   = (const float*)d_in[11];

    float* ws   = (float*)d_ws;
    float* xn3  = ws + XN3_OFF;
    unsigned* flux16 = (unsigned*)(ws + FLUX_OFF);
    float4* se4 = (float4*)(ws + FLUX_OFF);       // overlays flux region (used only pre-layers)
    int* wsi    = (int*)d_ws;
    int* deg    = wsi + DEG_OFF;
    int* rowptr = wsi + RP_OFF;
    int* fpos   = wsi + FP_OFF;
    int* posI   = wsi + POSI_OFF;
    int* posJ   = wsi + POSJ_OFF;

    float* out  = (float*)d_out;
    float* fluxOut = out + 3*9*N_NODES;

    precompute_kernel<<<64, 256, 0, stream>>>(K2N, K2E, KE1, KE2, KNc, ws, deg);
    count_kernel<<<N_EDGES/256, 256, 0, stream>>>(iInd, jInd, deg);
    scan_kernel<<<1, 256, 0, stream>>>(deg, rowptr, fpos);
    fill_kernel<<<N_EDGES/256, 256, 0, stream>>>(iInd, jInd, fpos, posI, posJ);

    open_kernel<<<32 + N_EDGES/256, 256, 0, stream>>>(
        xnV, xeV, Q, K1N, K1E, ws, posI, posJ, xn3, se4);
    open_gather_kernel<<<N_NODES/256, 256, 0, stream>>>(se4, rowptr, xn3);

    for (int l = 0; l < 5; ++l) {
        const float* mitg = ws + MIT_OFF + l*5760;
        bool mw3 = (l % 2 == 0);          // layers 0,2,4 -> MW=3 ; layers 1,3 -> MW=2 (A/B)
        if (l == 4) {
            edge_compute_kernel<true, 3><<<N_EDGES*2/256, 256, 0, stream>>>(
                xn3, iInd, jInd, posI, posJ, Q, mitg, flux16, fluxOut);
        } else if (mw3) {
            edge_compute_kernel<false, 3><<<N_EDGES*2/256, 256, 0, stream>>>(
                xn3, iInd, jInd, posI, posJ, Q, mitg, flux16, nullptr);
        } else {
            edge_compute_kernel<false, 2><<<N_EDGES*2/256, 256, 0, stream>>>(
                xn3, iInd, jInd, posI, posJ, Q, mitg, flux16, nullptr);
        }
        if (l < 4)
            node_gather_kernel<<<N_NODES, 64, 0, stream>>>((const __fp16*)flux16, rowptr, xn3);
        else
            node_gather_close_kernel<<<N_NODES, 64, 0, stream>>>(
                (const __fp16*)flux16, rowptr, xn3, ws, out);
    }
}

// Round 18
// 262.178 us; speedup vs baseline: 1.1305x; 1.1305x over previous
//
#include <hip/hip_runtime.h>

// Problem constants (fixed by setup_inputs)
#define N_NODES 8192
#define N_EDGES 65536
#define NS 64    // node state: 2 halves of 32 floats (27 used + pad); ch c class g at (c/9)*32+(c%9)*3+g
// flux16: CSR-slot layout [2E slots][64 halves] — one 128B cache line per endpoint contribution.

// Workspace layout (word offsets into d_ws)
#define XN3_OFF   0                                   // [8192][64] floats
#define MIT_OFF   (N_NODES*NS)                        // [5][2 stages][36 c][4 q][20] floats
#define K2N_OFF   (MIT_OFF + 5*5760)                  // [2][16][16]
#define KNC_OFF   (K2N_OFF + 2*16*16)                 // [2][3][18]
#define K2E_OFF   (KNC_OFF + 2*3*18)                  // [2]
#define FLUX_OFF  553728                              // 16B-aligned; [2E][32] u32 (fp16 pairs)
#define FLUX_END  (FLUX_OFF + 2*N_EDGES*32)
#define DEG_OFF   FLUX_END
#define RP_OFF    (DEG_OFF + N_NODES)
#define FP_OFF    (RP_OFF + N_NODES + 1)
#define POSI_OFF  (FP_OFF + N_NODES)
#define POSJ_OFF  (POSI_OFF + N_EDGES)

typedef float f32x2 __attribute__((ext_vector_type(2)));
typedef __fp16 fp16x2 __attribute__((ext_vector_type(2)));

__device__ __forceinline__ unsigned pkrtz(float a, float b) {
    fp16x2 h = __builtin_amdgcn_cvt_pkrtz(a, b);
    return *(unsigned*)&h;
}

template<int SLOT>
__device__ __forceinline__ float qb(float x) {
    int r = __builtin_amdgcn_update_dpp(0, __float_as_int(x), SLOT * 0x55, 0xf, 0xf, true);
    return __int_as_float(r);
}
__device__ __forceinline__ float qswap2(float x) {
    int r = __builtin_amdgcn_update_dpp(0, __float_as_int(x), 0x4E, 0xf, 0xf, true);
    return __int_as_float(r);
}

__device__ __forceinline__ void vrelu_p(float& a0, f32x2& a12,
                                        float q0, f32x2 q12, float iq2) {
    float t = fmaf(a0, q0, fmaf(a12.x, q12.x, a12.y * q12.y));
    float r = t > 0.f ? t * iq2 : 0.f;
    a0 = fmaf(-r, q0, a0);
    f32x2 nr = {-r, -r};
    a12 = nr * q12 + a12;
}

__device__ __forceinline__ void vrelu3(float& x0, float& x1, float& x2,
                                       float q0, float q1, float q2, float iq2) {
    float t = x0*q0 + x1*q1 + x2*q2;
    float r = t > 0.f ? t*iq2 : 0.f;
    x0 = fmaf(-r, q0, x0);
    x1 = fmaf(-r, q1, x1);
    x2 = fmaf(-r, q2, x2);
}

// one quarter of the 36-channel matvec for TWO edges sharing each LDS matrix row read.
template<int QS>
__device__ __forceinline__ void matvec2(const float* __restrict__ mbase, int q,
        const float (&v0a)[9], const f32x2 (&v12a)[9],
        const float (&v0b)[9], const f32x2 (&v12b)[9],
        f32x2 (&a0pa)[4], float& a0sa, f32x2 (&a12a)[9],
        f32x2 (&a0pb)[4], float& a0sb, f32x2 (&a12b)[9]) {
    const float* rb = mbase + QS*720 + q*20;
#pragma unroll
    for (int kc = 0; kc < 9; ++kc) {
        float b0a = qb<QS>(v0a[kc]);
        f32x2 b12a; b12a.x = qb<QS>(v12a[kc].x); b12a.y = qb<QS>(v12a[kc].y);
        float b0b = qb<QS>(v0b[kc]);
        f32x2 b12b; b12b.x = qb<QS>(v12b[kc].x); b12b.y = qb<QS>(v12b[kc].y);
        f32x2 bb0a = {b0a, b0a};
        f32x2 bb0b = {b0b, b0b};
        const float4* rp = (const float4*)(rb + kc*80);
        float4 R0 = rp[0], R1 = rp[1], R2 = rp[2], R3 = rp[3], R4 = rp[4];
        f32x2 m0p[4] = {{R0.x,R0.y},{R0.z,R0.w},{R1.x,R1.y},{R1.z,R1.w}};
        float mA[9] = {R2.z,R2.w,R3.x,R3.y,R3.z,R3.w,R4.x,R4.y,R4.z};
#pragma unroll
        for (int k = 0; k < 4; ++k) {
            a0pa[k] = m0p[k] * bb0a + a0pa[k];
            a0pb[k] = m0p[k] * bb0b + a0pb[k];
        }
        a0sa = fmaf(R2.x, b0a, a0sa);
        a0sb = fmaf(R2.x, b0b, a0sb);
#pragma unroll
        for (int k = 0; k < 9; ++k) {
            f32x2 mm = {mA[k], mA[k]};
            a12a[k] = mm * b12a + a12a[k];
            a12b[k] = mm * b12b + a12b[k];
        }
    }
}

// ---------------- precompute reduced matrices (+ zero deg) ----------------
__global__ void precompute_kernel(const float* __restrict__ K2N,
                                  const float* __restrict__ K2E,
                                  const float* __restrict__ KE1,
                                  const float* __restrict__ KE2,
                                  const float* __restrict__ KNc,
                                  float* __restrict__ ws,
                                  int* __restrict__ deg) {
    int tid = blockIdx.x * blockDim.x + threadIdx.x;
    int nthr = gridDim.x * blockDim.x;
    if (tid < N_NODES) deg[tid] = 0;
    for (int m = tid; m < 1440; m += nthr) {
        ws[MIT_OFF + m*20 + 9]  = 0.f;
        ws[MIT_OFF + m*20 + 19] = 0.f;
    }
    for (int m = tid; m < 5*1296; m += nthr) {
        int l = m / 1296, oc = m % 1296;
        int o = oc / 36, c = oc % 36;
        int qq = o / 9, k = o % 9;
        const float* p1 = KE1 + (size_t)(l*1296 + oc)*6;
        const float* p2 = KE2 + (size_t)(l*1296 + oc)*6;
        int base = MIT_OFF + l*5760 + (c*4 + qq)*20;
        ws[base + k]             = p1[0] + p1[1] + p1[2];
        ws[base + 10 + k]        = p1[3] + p1[4] + p1[5];
        ws[base + 2880 + k]      = p2[0] + p2[1] + p2[2];
        ws[base + 2880 + 10 + k] = p2[3] + p2[4] + p2[5];
    }
    for (int m = tid; m < 2*256; m += nthr) {
        int s = m / 256, oc = m % 256;
        const float* p = K2N + oc*6 + 3*s;
        ws[K2N_OFF + m] = p[0] + p[1] + p[2];
    }
    for (int m = tid; m < 2*54; m += nthr) {
        int s = m / 54, oc = m % 54;
        const float* p = KNc + oc*6 + 3*s;
        ws[KNC_OFF + m] = p[0] + p[1] + p[2];
    }
    if (tid < 2) {
        const float* p = K2E + 3*tid;
        ws[K2E_OFF + tid] = p[0] + p[1] + p[2];
    }
}

// ---------------- CSR build ----------------
__global__ void count_kernel(const int* __restrict__ iInd, const int* __restrict__ jInd,
                             int* __restrict__ deg) {
    int e = blockIdx.x * blockDim.x + threadIdx.x;
    if (e >= N_EDGES) return;
    atomicAdd(&deg[iInd[e]], 1);
    atomicAdd(&deg[jInd[e]], 1);
}

__global__ void scan_kernel(const int* __restrict__ deg, int* __restrict__ rowptr,
                            int* __restrict__ fpos) {
    __shared__ int lds[256];
    int t = threadIdx.x;
    int base = t * 32;
    int s = 0;
#pragma unroll
    for (int k = 0; k < 32; ++k) s += deg[base + k];
    lds[t] = s;
    __syncthreads();
    if (t == 0) {
        int run = 0;
        for (int k = 0; k < 256; ++k) { int v = lds[k]; lds[k] = run; run += v; }
        rowptr[N_NODES] = run;
    }
    __syncthreads();
    int off = lds[t];
#pragma unroll
    for (int k = 0; k < 32; ++k) {
        rowptr[base + k] = off;
        fpos[base + k] = off;
        off += deg[base + k];
    }
}

__global__ void fill_kernel(const int* __restrict__ iInd, const int* __restrict__ jInd,
                            int* __restrict__ fpos,
                            int* __restrict__ posI, int* __restrict__ posJ) {
    int e = blockIdx.x * blockDim.x + threadIdx.x;
    if (e >= N_EDGES) return;
    posI[e] = atomicAdd(&fpos[iInd[e]], 1);
    posJ[e] = atomicAdd(&fpos[jInd[e]], 1);
}

// ---------------- opening: node (blocks 0..31) + edge (blocks 32..287) ----------------
__global__ void open_kernel(const float* __restrict__ xnV,
                            const float* __restrict__ xeV,
                            const float* __restrict__ Q,
                            const float* __restrict__ K1N,
                            const float* __restrict__ K1E,
                            const float* __restrict__ ws,
                            const int* __restrict__ posI, const int* __restrict__ posJ,
                            float* __restrict__ xn3,
                            float4* __restrict__ seslot) {
    float q0 = Q[0], q1 = Q[1], q2 = Q[2];
    float iq2 = 1.f / (q0*q0 + q1*q1 + q2*q2);

    if (blockIdx.x < 32) {
        int n = blockIdx.x * 256 + threadIdx.x;
        float R[3][9];
#pragma unroll
        for (int c = 0; c < 3; ++c)
#pragma unroll
            for (int p = 0; p < 9; ++p)
                R[c][p] = xnV[(c*9 + p)*N_NODES + n];
#pragma unroll
        for (int c = 0; c < 3; ++c)
#pragma unroll
            for (int v = 0; v < 3; ++v)
                vrelu3(R[c][3*v], R[c][3*v+1], R[c][3*v+2], q0, q1, q2, iq2);

        float s[16][3];
#pragma unroll
        for (int o = 0; o < 16; ++o) {
            float a0 = 0.f, a1 = 0.f, a2 = 0.f;
#pragma unroll
            for (int c = 0; c < 3; ++c)
#pragma unroll
                for (int g = 0; g < 3; ++g) {
                    a0 = fmaf(R[c][3*g + 0], K1N[(o*3 + c)*6 + g],     a0);
                    a1 = fmaf(R[c][3*g + 1], K1N[(o*3 + c)*6 + 3 + g], a1);
                    a2 = fmaf(R[c][3*g + 2], K1N[(o*3 + c)*6 + 3 + g], a2);
                }
            s[o][0] = a0; s[o][1] = a1; s[o][2] = a2;
        }
#pragma unroll
        for (int o = 0; o < 16; ++o)
            vrelu3(s[o][0], s[o][1], s[o][2], q0, q1, q2, iq2);

        float u[16][3];
#pragma unroll
        for (int o = 0; o < 16; ++o) {
            float a0 = 0.f, a1 = 0.f, a2 = 0.f;
#pragma unroll
            for (int c = 0; c < 16; ++c) {
                float m0 = ws[K2N_OFF + o*16 + c];
                float mA = ws[K2N_OFF + 256 + o*16 + c];
                a0 = fmaf(m0, s[c][0], a0);
                a1 = fmaf(mA, s[c][1], a1);
                a2 = fmaf(mA, s[c][2], a2);
            }
            u[o][0] = a0; u[o][1] = a1; u[o][2] = a2;
            vrelu3(u[o][0], u[o][1], u[o][2], q0, q1, q2, iq2);
        }

        float* dst = xn3 + n*NS;
#pragma unroll
        for (int o = 0; o < 16; ++o) {
            int base = (o/9)*32 + (o%9)*3;
#pragma unroll
            for (int g = 0; g < 3; ++g)
                dst[base + g] = u[o][g];
        }
#pragma unroll
        for (int k = 27; k < 32; ++k) dst[k] = 0.f;
    } else {
        int e = (blockIdx.x - 32) * 256 + threadIdx.x;
        float R[9];
#pragma unroll
        for (int p = 0; p < 9; ++p) R[p] = xeV[p*N_EDGES + e];
#pragma unroll
        for (int v = 0; v < 3; ++v)
            vrelu3(R[3*v], R[3*v+1], R[3*v+2], q0, q1, q2, iq2);

        float s0 = 0.f, s1 = 0.f, s2 = 0.f;
#pragma unroll
        for (int g = 0; g < 3; ++g) {
            s0 = fmaf(R[3*g + 0], K1E[g],     s0);
            s1 = fmaf(R[3*g + 1], K1E[3 + g], s1);
            s2 = fmaf(R[3*g + 2], K1E[3 + g], s2);
        }
        vrelu3(s0, s1, s2, q0, q1, q2, iq2);
        s0 *= ws[K2E_OFF + 0];
        s1 *= ws[K2E_OFF + 1];
        s2 *= ws[K2E_OFF + 1];
        vrelu3(s0, s1, s2, q0, q1, q2, iq2);

        seslot[posI[e]] = make_float4( s0,  s1,  s2,  1.f);
        seslot[posJ[e]] = make_float4(-s0, -s1, -s2, -1.f);
    }
}

// gather edge-open contributions into xn3 channels 16,17 — streaming CSR reads
__global__ void open_gather_kernel(const float4* __restrict__ seslot,
                                   const int* __restrict__ rowptr,
                                   float* __restrict__ xn3) {
    int n = blockIdx.x * blockDim.x + threadIdx.x;
    if (n >= N_NODES) return;
    int beg = rowptr[n], end = rowptr[n + 1];
    float d0 = 0.f, d1 = 0.f, d2 = 0.f, a0 = 0.f, a1 = 0.f, a2 = 0.f;
    for (int d = beg; d < end; ++d) {
        float4 v = seslot[d];
        d0 += v.x; d1 += v.y; d2 += v.z;
        float hs = 0.5f * v.w;
        a0 = fmaf(hs, v.x, a0); a1 = fmaf(hs, v.y, a1); a2 = fmaf(hs, v.z, a2);
    }
    float* dst = xn3 + n*NS;
    dst[53] = d0; dst[54] = d1; dst[55] = d2;
    dst[56] = a0; dst[57] = a1; dst[58] = a2;
#pragma unroll
    for (int k = 59; k < 64; ++k) dst[k] = 0.f;
}

// ---------------- per-layer phase A: 2 edges per thread-quad member (proven best) ----------------
template<bool WRITE_FLUX>
__global__ __launch_bounds__(256, 2) void edge_compute_kernel(
        const float* __restrict__ xn3,
        const int* __restrict__ iInd, const int* __restrict__ jInd,
        const int* __restrict__ posI, const int* __restrict__ posJ,
        const float* __restrict__ Q,
        const float* __restrict__ mitg,   // [2][36][4][20]
        unsigned* __restrict__ flux16, float* __restrict__ fluxOut) {
    __shared__ float mit[5760];
    {
        const float4* s4 = (const float4*)mitg;
        float4* d4 = (float4*)mit;
        for (int t = threadIdx.x; t < 1440; t += 256) d4[t] = s4[t];
    }
    __syncthreads();

    int tid = blockIdx.x * 256 + threadIdx.x;
    int qd = tid >> 2, q = tid & 3;
    int e0 = qd << 1, e1 = e0 | 1;
    float q0 = Q[0];
    f32x2 q12 = {Q[1], Q[2]};
    float iq2 = 1.f / (q0*q0 + q12.x*q12.x + q12.y*q12.y);
    int hofs = 32*(q & 1);
    const float4* xi0 = (const float4*)(xn3 + iInd[e0]*NS + hofs);
    const float4* xj0 = (const float4*)(xn3 + jInd[e0]*NS + hofs);
    const float4* xi1 = (const float4*)(xn3 + iInd[e1]*NS + hofs);
    const float4* xj1 = (const float4*)(xn3 + jInd[e1]*NS + hofs);

    bool isAve = q >= 2;
    float sA = isAve ? 0.5f :  1.f;
    float sB = isAve ? 0.5f : -1.f;

    float vvA[28], vvB[28];
#pragma unroll
    for (int t = 0; t < 7; ++t) {
        float4 a = xi0[t], b = xj0[t];
        vvA[4*t+0] = fmaf(sA, a.x, sB * b.x);
        vvA[4*t+1] = fmaf(sA, a.y, sB * b.y);
        vvA[4*t+2] = fmaf(sA, a.z, sB * b.z);
        vvA[4*t+3] = fmaf(sA, a.w, sB * b.w);
        float4 c = xi1[t], d = xj1[t];
        vvB[4*t+0] = fmaf(sA, c.x, sB * d.x);
        vvB[4*t+1] = fmaf(sA, c.y, sB * d.y);
        vvB[4*t+2] = fmaf(sA, c.z, sB * d.z);
        vvB[4*t+3] = fmaf(sA, c.w, sB * d.w);
    }

    float v0a[9], v0b[9]; f32x2 v12a[9], v12b[9];
#pragma unroll
    for (int k = 0; k < 9; ++k) {
        v0a[k]    = vvA[3*k];
        v12a[k].x = vvA[3*k+1];
        v12a[k].y = vvA[3*k+2];
        vrelu_p(v0a[k], v12a[k], q0, q12, iq2);
        v0b[k]    = vvB[3*k];
        v12b[k].x = vvB[3*k+1];
        v12b[k].y = vvB[3*k+2];
        vrelu_p(v0b[k], v12b[k], q0, q12, iq2);
    }

    f32x2 a0pa[4], a0pb[4]; float a0sa, a0sb; f32x2 a12a[9], a12b[9];
#pragma unroll
    for (int k = 0; k < 4; ++k) { a0pa[k] = (f32x2){0.f,0.f}; a0pb[k] = (f32x2){0.f,0.f}; }
    a0sa = 0.f; a0sb = 0.f;
#pragma unroll
    for (int k = 0; k < 9; ++k) { a12a[k] = (f32x2){0.f,0.f}; a12b[k] = (f32x2){0.f,0.f}; }
    matvec2<0>(mit, q, v0a, v12a, v0b, v12b, a0pa, a0sa, a12a, a0pb, a0sb, a12b);
    matvec2<1>(mit, q, v0a, v12a, v0b, v12b, a0pa, a0sa, a12a, a0pb, a0sb, a12b);
    matvec2<2>(mit, q, v0a, v12a, v0b, v12b, a0pa, a0sa, a12a, a0pb, a0sb, a12b);
    matvec2<3>(mit, q, v0a, v12a, v0b, v12b, a0pa, a0sa, a12a, a0pb, a0sb, a12b);
#pragma unroll
    for (int k = 0; k < 9; ++k) {
        float w0 = (k < 8) ? ((k & 1) ? a0pa[k>>1].y : a0pa[k>>1].x) : a0sa;
        f32x2 w12 = a12a[k];
        vrelu_p(w0, w12, q0, q12, iq2);
        v0a[k] = w0; v12a[k] = w12;
        float u0 = (k < 8) ? ((k & 1) ? a0pb[k>>1].y : a0pb[k>>1].x) : a0sb;
        f32x2 u12 = a12b[k];
        vrelu_p(u0, u12, q0, q12, iq2);
        v0b[k] = u0; v12b[k] = u12;
    }
#pragma unroll
    for (int k = 0; k < 4; ++k) { a0pa[k] = (f32x2){0.f,0.f}; a0pb[k] = (f32x2){0.f,0.f}; }
    a0sa = 0.f; a0sb = 0.f;
#pragma unroll
    for (int k = 0; k < 9; ++k) { a12a[k] = (f32x2){0.f,0.f}; a12b[k] = (f32x2){0.f,0.f}; }
    matvec2<0>(mit + 2880, q, v0a, v12a, v0b, v12b, a0pa, a0sa, a12a, a0pb, a0sb, a12b);
    matvec2<1>(mit + 2880, q, v0a, v12a, v0b, v12b, a0pa, a0sa, a12a, a0pb, a0sb, a12b);
    matvec2<2>(mit + 2880, q, v0a, v12a, v0b, v12b, a0pa, a0sa, a12a, a0pb, a0sb, a12b);
    matvec2<3>(mit + 2880, q, v0a, v12a, v0b, v12b, a0pa, a0sa, a12a, a0pb, a0sb, a12b);

#pragma unroll
    for (int k = 0; k < 9; ++k) {
        float w0 = (k < 8) ? ((k & 1) ? a0pa[k>>1].y : a0pa[k>>1].x) : a0sa;
        f32x2 w12 = a12a[k];
        vrelu_p(w0, w12, q0, q12, iq2);
        v0a[k] = w0; v12a[k] = w12;
        float u0 = (k < 8) ? ((k & 1) ? a0pb[k>>1].y : a0pb[k>>1].x) : a0sb;
        f32x2 u12 = a12b[k];
        vrelu_p(u0, u12, q0, q12, iq2);
        v0b[k] = u0; v12b[k] = u12;
    }

    float selO = (q < 2) ? 1.f  : 0.5f;
    float selP = (q < 2) ? 0.5f : -1.f;
    {
        float o27[27];
        unsigned pk[16];
#pragma unroll
        for (int k = 0; k < 9; ++k) {
            float o0 = qswap2(v0a[k]);
            float o1 = qswap2(v12a[k].x);
            float o2 = qswap2(v12a[k].y);
            o27[3*k]   = fmaf(selO, v0a[k],    selP * o0);
            o27[3*k+1] = fmaf(selO, v12a[k].x, selP * o1);
            o27[3*k+2] = fmaf(selO, v12a[k].y, selP * o2);
        }
#pragma unroll
        for (int t = 0; t < 13; ++t) pk[t] = pkrtz(o27[2*t], o27[2*t+1]);
        pk[13] = pkrtz(o27[26], 0.f);
        pk[14] = 0u; pk[15] = 0u;
        int slot = (q < 2) ? posI[e0] : posJ[e0];
        uint4* dst = (uint4*)(flux16 + (size_t)slot*32 + (q & 1)*16);
        dst[0] = make_uint4(pk[0],  pk[1],  pk[2],  pk[3]);
        dst[1] = make_uint4(pk[4],  pk[5],  pk[6],  pk[7]);
        dst[2] = make_uint4(pk[8],  pk[9],  pk[10], pk[11]);
        dst[3] = make_uint4(pk[12], pk[13], pk[14], pk[15]);
    }
    {
        float o27[27];
        unsigned pk[16];
#pragma unroll
        for (int k = 0; k < 9; ++k) {
            float o0 = qswap2(v0b[k]);
            float o1 = qswap2(v12b[k].x);
            float o2 = qswap2(v12b[k].y);
            o27[3*k]   = fmaf(selO, v0b[k],    selP * o0);
            o27[3*k+1] = fmaf(selO, v12b[k].x, selP * o1);
            o27[3*k+2] = fmaf(selO, v12b[k].y, selP * o2);
        }
#pragma unroll
        for (int t = 0; t < 13; ++t) pk[t] = pkrtz(o27[2*t], o27[2*t+1]);
        pk[13] = pkrtz(o27[26], 0.f);
        pk[14] = 0u; pk[15] = 0u;
        int slot = (q < 2) ? posI[e1] : posJ[e1];
        uint4* dst = (uint4*)(flux16 + (size_t)slot*32 + (q & 1)*16);
        dst[0] = make_uint4(pk[0],  pk[1],  pk[2],  pk[3]);
        dst[1] = make_uint4(pk[4],  pk[5],  pk[6],  pk[7]);
        dst[2] = make_uint4(pk[8],  pk[9],  pk[10], pk[11]);
        dst[3] = make_uint4(pk[12], pk[13], pk[14], pk[15]);
    }

    if (WRITE_FLUX) {
#pragma unroll
        for (int k = 0; k < 9; ++k) {
#pragma unroll
            for (int p = 0; p < 9; ++p) {
                float wa = (p % 3 == 0) ? v0a[k] : (p % 3 == 1) ? v12a[k].x : v12a[k].y;
                fluxOut[((size_t)((9*q + k)*9 + p))*N_EDGES + e0] = wa;
                float wb = (p % 3 == 0) ? v0b[k] : (p % 3 == 1) ? v12b[k].x : v12b[k].y;
                fluxOut[((size_t)((9*q + k)*9 + p))*N_EDGES + e1] = wb;
            }
        }
    }
}

// ---------------- per-layer phase B: wave-per-node streaming fp16 gather + xn update ----------------
// 256-thread blocks, 4 waves each handling one node (fewer blocks -> less dispatch ramp)
__global__ __launch_bounds__(256) void node_gather_kernel(
        const __fp16* __restrict__ flux16,
        const int* __restrict__ rowptr,
        float* __restrict__ xn3) {
    int n = blockIdx.x * 4 + (threadIdx.x >> 6);
    int l = threadIdx.x & 63;
    int beg = rowptr[n], end = rowptr[n + 1];
    const __fp16* p = flux16 + (size_t)beg * 64 + l;
    float acc = 0.f, acc2 = 0.f;
    int d = beg;
    for (; d + 2 <= end; d += 2) {
        acc  += (float)p[0];
        acc2 += (float)p[64];
        p += 128;
    }
    if (d < end) acc += (float)p[0];
    acc += acc2;
    if ((l & 31) < 27) {
        float* x = xn3 + n*NS + l;
        *x = fmaf(-0.1f, acc, *x);
    }
}

// ---------------- layer-4 phase B fused with close ----------------
__global__ __launch_bounds__(64) void node_gather_close_kernel(
        const __fp16* __restrict__ flux16,
        const int* __restrict__ rowptr,
        const float* __restrict__ xn3,
        const float* __restrict__ ws,     // KNC at KNC_OFF
        float* __restrict__ out) {
    __shared__ float xl[64];
    int n = blockIdx.x;
    int l = threadIdx.x;
    int beg = rowptr[n], end = rowptr[n + 1];
    const __fp16* p = flux16 + (size_t)beg * 64 + l;
    float acc = 0.f, acc2 = 0.f;
    int d = beg;
    for (; d + 2 <= end; d += 2) {
        acc  += (float)p[0];
        acc2 += (float)p[64];
        p += 128;
    }
    if (d < end) acc += (float)p[0];
    acc += acc2;
    float xv = 0.f;
    if ((l & 31) < 27)
        xv = fmaf(-0.1f, acc, xn3[n*NS + l]);
    xl[l] = xv;
    __syncthreads();

    if (l < 27) {
        int oo = l / 9, pp = l % 9, g = pp % 3;
        int mbase = KNC_OFF + (g == 0 ? 0 : 54) + oo*18;
        float a = 0.f;
#pragma unroll
        for (int c = 0; c < 18; ++c)
            a = fmaf(ws[mbase + c], xl[(c/9)*32 + (c%9)*3 + g], a);
        out[(oo*9 + pp)*N_NODES + n] = a;
    }
}

extern "C" void kernel_launch(void* const* d_in, const int* in_sizes, int n_in,
                              void* d_out, int out_size, void* d_ws, size_t ws_size,
                              hipStream_t stream) {
    const float* xnV = (const float*)d_in[0];
    const float* xeV = (const float*)d_in[1];
    const int*   iInd = (const int*)d_in[2];
    const int*   jInd = (const int*)d_in[3];
    const float* K1N = (const float*)d_in[4];
    const float* K2N = (const float*)d_in[5];
    const float* K1E = (const float*)d_in[6];
    const float* K2E = (const float*)d_in[7];
    const float* KE1 = (const float*)d_in[8];
    const float* KE2 = (const float*)d_in[9];
    const float* KNc = (const float*)d_in[10];
    const float* Q   = (const float*)d_in[11];

    float* ws   = (float*)d_ws;
    float* xn3  = ws + XN3_OFF;
    unsigned* flux16 = (unsigned*)(ws + FLUX_OFF);
    float4* se4 = (float4*)(ws + FLUX_OFF);       // overlays flux region (used only pre-layers)
    int* wsi    = (int*)d_ws;
    int* deg    = wsi + DEG_OFF;
    int* rowptr = wsi + RP_OFF;
    int* fpos   = wsi + FP_OFF;
    int* posI   = wsi + POSI_OFF;
    int* posJ   = wsi + POSJ_OFF;

    float* out  = (float*)d_out;
    float* fluxOut = out + 3*9*N_NODES;

    precompute_kernel<<<64, 256, 0, stream>>>(K2N, K2E, KE1, KE2, KNc, ws, deg);
    count_kernel<<<N_EDGES/256, 256, 0, stream>>>(iInd, jInd, deg);
    scan_kernel<<<1, 256, 0, stream>>>(deg, rowptr, fpos);
    fill_kernel<<<N_EDGES/256, 256, 0, stream>>>(iInd, jInd, fpos, posI, posJ);

    open_kernel<<<32 + N_EDGES/256, 256, 0, stream>>>(
        xnV, xeV, Q, K1N, K1E, ws, posI, posJ, xn3, se4);
    open_gather_kernel<<<N_NODES/256, 256, 0, stream>>>(se4, rowptr, xn3);

    for (int l = 0; l < 5; ++l) {
        const float* mitg = ws + MIT_OFF + l*5760;
        if (l == 4)
            edge_compute_kernel<true><<<N_EDGES*2/256, 256, 0, stream>>>(
                xn3, iInd, jInd, posI, posJ, Q, mitg, flux16, fluxOut);
        else
            edge_compute_kernel<false><<<N_EDGES*2/256, 256, 0, stream>>>(
                xn3, iInd, jInd, posI, posJ, Q, mitg, flux16, nullptr);
        if (l < 4)
            node_gather_kernel<<<N_NODES/4, 256, 0, stream>>>((const __fp16*)flux16, rowptr, xn3);
        else
            node_gather_close_kernel<<<N_NODES, 64, 0, stream>>>(
                (const __fp16*)flux16, rowptr, xn3, ws, out);
    }
}